// Round 1
// baseline (1627.522 us; speedup 1.0000x reference)
//
#include <hip/hip_runtime.h>
#include <hip/hip_bf16.h>
#include <stdint.h>

#define NN 100000
#define NE 1600000
#define HID 256
#define NGRAPH 64
#define POOL_BLOCKS 256

typedef __attribute__((ext_vector_type(8))) short short8;
typedef __attribute__((ext_vector_type(4))) float f32x4;
typedef __attribute__((ext_vector_type(4))) unsigned int u32x4;

static __device__ inline float bf2f(unsigned short u){
  union { unsigned int i; float f; } x; x.i = ((unsigned int)u) << 16; return x.f;
}
static __device__ inline unsigned short f2bf(float f){
  union { float f; unsigned int i; } x; x.f = f;
  unsigned int r = x.i + 0x7fffu + ((x.i >> 16) & 1u);
  return (unsigned short)(r >> 16);
}

static __device__ inline void gload16(const void* g, void* l){
  __builtin_amdgcn_global_load_lds((const __attribute__((address_space(1))) void*)g,
                                   (__attribute__((address_space(3))) void*)l, 16, 0, 0);
}

// ---------------- GEMM: C[M,256] = A[M,K] @ W[K,256] (+bias, relu), bf16 out ----
// WT is W transposed+padded: [256][Kp] bf16. A is f32 (F32A, reg-staged convert)
// or bf16 (global_load_lds). 8 waves, block tile 128x256, wave tile 64x64, BK=64.
// LDS XOR swizzle: chunk ^= (row&7) on both store-source and read.
template<bool F32A>
__global__ __launch_bounds__(512) void gemm_k(
    const void* __restrict__ Aq, int lda, int K, int Kp,
    const unsigned short* __restrict__ WT,
    const float* __restrict__ bias,
    unsigned short* __restrict__ C, int ldc, int M, int relu)
{
  __shared__ unsigned char smem[49152];   // A: [128][64] bf16 = 16KB, B: [256][64] bf16 = 32KB
  const int tid  = threadIdx.x;
  const int lane = tid & 63;
  const int wid  = tid >> 6;
  const int wm   = wid >> 2;    // 0..1
  const int wn   = wid & 3;     // 0..3
  const int bm   = blockIdx.x * 128;
  const int l15  = lane & 15;
  const int lk   = lane >> 4;   // 0..3

  f32x4 acc[4][4];
#pragma unroll
  for (int i = 0; i < 4; i++)
#pragma unroll
    for (int j = 0; j < 4; j++) acc[i][j] = (f32x4){0.f, 0.f, 0.f, 0.f};

  for (int k0 = 0; k0 < Kp; k0 += 64) {
    __syncthreads();
    if (F32A) {
      const float* A = (const float*)Aq;
#pragma unroll
      for (int it = 0; it < 2; ++it) {
        int chunk = it * 512 + tid;       // 1024 chunks of 16B = 128 rows x 8
        int row = chunk >> 3;
        int c   = chunk & 7;
        int gr  = bm + row; if (gr >= M) gr = M - 1;
        int cg  = c ^ (row & 7);          // pre-swizzled source chunk
        int kb  = k0 + cg * 8;
        const float* ap = A + (size_t)gr * lda;
        u32x4 pk;
#pragma unroll
        for (int hh = 0; hh < 4; ++hh) {
          int ka = kb + 2 * hh, kc = kb + 2 * hh + 1;
          float v0 = (ka < K) ? ap[ka] : 0.f;
          float v1 = (kc < K) ? ap[kc] : 0.f;
          pk[hh] = (unsigned int)f2bf(v0) | ((unsigned int)f2bf(v1) << 16);
        }
        *(u32x4*)(smem + row * 128 + c * 16) = pk;
      }
    } else {
      const unsigned short* A = (const unsigned short*)Aq;
#pragma unroll
      for (int it = 0; it < 2; ++it) {
        int inst = wid * 2 + it;          // 16 instrs x 1KB = 16KB
        int row  = inst * 8 + (lane >> 3);
        int c    = lane & 7;
        int gr   = bm + row; if (gr >= M) gr = M - 1;
        int cg   = c ^ (row & 7);
        gload16(A + (size_t)gr * lda + k0 + cg * 8, smem + inst * 1024);
      }
    }
    // B tile: 256 rows (out-cols) x 64 k, via global_load_lds, pre-swizzled source
#pragma unroll
    for (int it = 0; it < 4; ++it) {
      int inst = wid * 4 + it;            // 32 instrs x 1KB = 32KB
      int nr   = inst * 8 + (lane >> 3);
      int c    = lane & 7;
      int cg   = c ^ (nr & 7);
      gload16(WT + (size_t)nr * Kp + k0 + cg * 8, smem + 16384 + inst * 1024);
    }
    __syncthreads();

#pragma unroll
    for (int s2 = 0; s2 < 2; ++s2) {
      short8 a[4], b[4];
#pragma unroll
      for (int i = 0; i < 4; i++) {
        int row = wm * 64 + i * 16 + l15;
        int ch  = (s2 * 4 + lk) ^ (row & 7);
        a[i] = *(const short8*)(smem + row * 128 + ch * 16);
      }
#pragma unroll
      for (int j = 0; j < 4; j++) {
        int col = wn * 64 + j * 16 + l15;
        int ch  = (s2 * 4 + lk) ^ (col & 7);
        b[j] = *(const short8*)(smem + 16384 + col * 128 + ch * 16);
      }
#pragma unroll
      for (int i = 0; i < 4; i++)
#pragma unroll
        for (int j = 0; j < 4; j++)
          acc[i][j] = __builtin_amdgcn_mfma_f32_16x16x32_bf16(a[i], b[j], acc[i][j], 0, 0, 0);
    }
  }

#pragma unroll
  for (int j = 0; j < 4; j++) {
    int col = wn * 64 + j * 16 + l15;
    float bv = bias ? bias[col] : 0.f;
#pragma unroll
    for (int i = 0; i < 4; i++) {
#pragma unroll
      for (int r = 0; r < 4; r++) {
        int row = bm + wm * 64 + i * 16 + lk * 4 + r;   // D: col=lane&15, row=(lane>>4)*4+r
        if (row < M) {
          float v = acc[i][j][r] + bv;
          if (relu) v = fmaxf(v, 0.f);
          C[(size_t)row * ldc + col] = f2bf(v);
        }
      }
    }
  }
}

// ---------------- weight transpose + pad + bf16 convert: WT[n][k] = W[k][n] ----
__global__ void wconv_k(const float* __restrict__ W, unsigned short* __restrict__ WT,
                        int K, int Kp)
{
  int idx = blockIdx.x * 256 + threadIdx.x;
  if (idx >= 256 * Kp) return;
  int n = idx / Kp, k = idx - n * Kp;
  float v = (k < K) ? W[(size_t)k * 256 + n] : 0.f;
  WT[(size_t)n * Kp + k] = f2bf(v);
}

// ---------------- CSR build ----------------
__global__ void zero_int_k(int* p, int n){
  int i = blockIdx.x * 256 + threadIdx.x; if (i < n) p[i] = 0;
}
__global__ void count_k(const int* __restrict__ dst, int* __restrict__ cnt, int n){
  int e = blockIdx.x * 256 + threadIdx.x; if (e < n) atomicAdd(&cnt[dst[e]], 1);
}
__global__ void deg_k(const int* __restrict__ cnt, float* __restrict__ dinv,
                      float* __restrict__ selfc, int n){
  int i = blockIdx.x * 256 + threadIdx.x;
  if (i < n) { float d = 1.0f + (float)cnt[i]; dinv[i] = rsqrtf(d); selfc[i] = 1.0f / d; }
}
__global__ void scan1_k(const int* __restrict__ cnt, int* __restrict__ bsum, int n){
  __shared__ int s[256];
  int b = blockIdx.x, t = threadIdx.x;
  int base = b * 1024 + t * 4, v = 0;
#pragma unroll
  for (int j = 0; j < 4; j++) { int i = base + j; if (i < n) v += cnt[i]; }
  s[t] = v; __syncthreads();
  for (int o = 128; o > 0; o >>= 1) { if (t < o) s[t] += s[t + o]; __syncthreads(); }
  if (t == 0) bsum[b] = s[0];
}
__global__ void scan2_k(int* bsum, int nb){
  __shared__ int s[256];
  int t = threadIdx.x;
  int v = (t < nb) ? bsum[t] : 0;
  s[t] = v; __syncthreads();
  for (int o = 1; o < 256; o <<= 1) {
    int x = (t >= o) ? s[t - o] : 0; __syncthreads();
    s[t] += x; __syncthreads();
  }
  if (t < nb) bsum[t] = s[t] - v;   // exclusive
}
__global__ void scan3_k(const int* __restrict__ cnt, const int* __restrict__ bsum,
                        int* __restrict__ rowstart, int* __restrict__ cursor, int n){
  __shared__ int s[256];
  int b = blockIdx.x, t = threadIdx.x;
  int base = b * 1024 + t * 4;
  int c0 = 0, c1 = 0, c2 = 0, c3 = 0;
  if (base + 0 < n) c0 = cnt[base + 0];
  if (base + 1 < n) c1 = cnt[base + 1];
  if (base + 2 < n) c2 = cnt[base + 2];
  if (base + 3 < n) c3 = cnt[base + 3];
  int ts = c0 + c1 + c2 + c3;
  s[t] = ts; __syncthreads();
  for (int o = 1; o < 256; o <<= 1) {
    int x = (t >= o) ? s[t - o] : 0; __syncthreads();
    s[t] += x; __syncthreads();
  }
  int run = bsum[b] + s[t] - ts;
  int cc[4] = {c0, c1, c2, c3};
#pragma unroll
  for (int j = 0; j < 4; j++) {
    int i = base + j;
    if (i < n) {
      rowstart[i] = run; cursor[i] = run; run += cc[j];
      if (i == n - 1) rowstart[n] = run;
    }
  }
}
__global__ void scatter_k(const int* __restrict__ src, const int* __restrict__ dst,
                          const float* __restrict__ dinv, int* __restrict__ cursor,
                          int* __restrict__ csr_src, float* __restrict__ csr_coef, int n){
  int e = blockIdx.x * 256 + threadIdx.x; if (e >= n) return;
  int d = dst[e], s = src[e];
  int p = atomicAdd(&cursor[d], 1);
  csr_src[p] = s;
  csr_coef[p] = dinv[s] * dinv[d];
}

// ---------------- aggregation: out = relu(sum_e coef*h[src] + selfc*h[dst] + b) --
__global__ __launch_bounds__(256) void agg_k(
    const unsigned short* __restrict__ h,
    const int* __restrict__ rowstart, const int* __restrict__ csr_src,
    const float* __restrict__ csr_coef, const float* __restrict__ selfc,
    const float* __restrict__ bias, unsigned short* __restrict__ out)
{
  int dst = blockIdx.x * 4 + (threadIdx.x >> 6);
  if (dst >= NN) return;
  int lane = threadIdx.x & 63;
  int colb = lane * 4;
  ushort4 hv = *(const ushort4*)(h + (size_t)dst * 256 + colb);
  float sc = selfc[dst];
  float a0 = sc * bf2f(hv.x), a1 = sc * bf2f(hv.y), a2 = sc * bf2f(hv.z), a3 = sc * bf2f(hv.w);
  int e0 = rowstart[dst], e1 = rowstart[dst + 1];
  int e = e0;
  for (; e + 1 < e1; e += 2) {
    int s0 = csr_src[e], s1 = csr_src[e + 1];
    float cf0 = csr_coef[e], cf1 = csr_coef[e + 1];
    ushort4 v0 = *(const ushort4*)(h + (size_t)s0 * 256 + colb);
    ushort4 v1 = *(const ushort4*)(h + (size_t)s1 * 256 + colb);
    a0 += cf0 * bf2f(v0.x); a1 += cf0 * bf2f(v0.y); a2 += cf0 * bf2f(v0.z); a3 += cf0 * bf2f(v0.w);
    a0 += cf1 * bf2f(v1.x); a1 += cf1 * bf2f(v1.y); a2 += cf1 * bf2f(v1.z); a3 += cf1 * bf2f(v1.w);
  }
  if (e < e1) {
    int s0 = csr_src[e]; float cf0 = csr_coef[e];
    ushort4 v0 = *(const ushort4*)(h + (size_t)s0 * 256 + colb);
    a0 += cf0 * bf2f(v0.x); a1 += cf0 * bf2f(v0.y); a2 += cf0 * bf2f(v0.z); a3 += cf0 * bf2f(v0.w);
  }
  float4 bv = *(const float4*)(bias + colb);
  a0 = fmaxf(a0 + bv.x, 0.f); a1 = fmaxf(a1 + bv.y, 0.f);
  a2 = fmaxf(a2 + bv.z, 0.f); a3 = fmaxf(a3 + bv.w, 0.f);
  ushort4 o; o.x = f2bf(a0); o.y = f2bf(a1); o.z = f2bf(a2); o.w = f2bf(a3);
  *(ushort4*)(out + (size_t)dst * 256 + colb) = o;
}

// ---------------- pooling partials ----------------
__global__ __launch_bounds__(256) void pool_k(
    const unsigned short* __restrict__ x, const int* __restrict__ batch,
    float* __restrict__ pp, float* __restrict__ cp)
{
  __shared__ float acc[NGRAPH][HID];   // 64KB
  __shared__ float cl[NGRAPH];
  int t = threadIdx.x, b = blockIdx.x;
  for (int i = t; i < NGRAPH * HID; i += 256) ((float*)acc)[i] = 0.f;
  if (t < NGRAPH) cl[t] = 0.f;
  __syncthreads();
  int per = (NN + POOL_BLOCKS - 1) / POOL_BLOCKS;
  int i0 = b * per, i1 = min(NN, i0 + per);
  for (int i = i0; i < i1; ++i) {
    int g = batch[i];
    acc[g][t] += bf2f(x[(size_t)i * 256 + t]);   // thread t owns column t: no race
    if (t == 0) cl[g] += 1.f;
  }
  __syncthreads();
  for (int g = 0; g < NGRAPH; ++g) pp[(size_t)b * (NGRAPH * HID) + g * HID + t] = acc[g][t];
  if (t < NGRAPH) cp[b * NGRAPH + t] = cl[t];
}

// ---------------- head: reduce partials, /cnt, 2-layer MLP, log_softmax --------
__global__ __launch_bounds__(256) void head_k(
    const float* __restrict__ pp, const float* __restrict__ cp,
    const float* __restrict__ Wl1, const float* __restrict__ bl1,
    const float* __restrict__ Wl2, const float* __restrict__ bl2,
    float* __restrict__ out)
{
  __shared__ float pooled[HID];
  __shared__ float red[2][4];
  int g = blockIdx.x, t = threadIdx.x;
  float s = 0.f;
  for (int b = 0; b < POOL_BLOCKS; ++b) s += pp[(size_t)b * (NGRAPH * HID) + g * HID + t];
  float cnt = 0.f;
  for (int b = 0; b < POOL_BLOCKS; ++b) cnt += cp[b * NGRAPH + g];
  pooled[t] = s / fmaxf(cnt, 1.f);
  __syncthreads();
  float hv = bl1[t];
  for (int k = 0; k < HID; ++k) hv += pooled[k] * Wl1[k * HID + t];
  hv = fmaxf(hv, 0.f);
  float p0 = hv * Wl2[t * 2 + 0];
  float p1 = hv * Wl2[t * 2 + 1];
  for (int o = 32; o > 0; o >>= 1) { p0 += __shfl_down(p0, o); p1 += __shfl_down(p1, o); }
  int w = t >> 6;
  if ((t & 63) == 0) { red[0][w] = p0; red[1][w] = p1; }
  __syncthreads();
  if (t == 0) {
    float l0 = bl2[0], l1 = bl2[1];
#pragma unroll
    for (int i = 0; i < 4; i++) { l0 += red[0][i]; l1 += red[1][i]; }
    float m = fmaxf(l0, l1);
    float lse = m + logf(expf(l0 - m) + expf(l1 - m));
    out[g * 2 + 0] = l0 - lse;
    out[g * 2 + 1] = l1 - lse;
  }
}

// ---------------- launch ----------------
extern "C" void kernel_launch(void* const* d_in, const int* in_sizes, int n_in,
                              void* d_out, int out_size, void* d_ws, size_t ws_size,
                              hipStream_t stream)
{
  const float* content = (const float*)d_in[0];
  const float* bert    = (const float*)d_in[1];
  const float* profile = (const float*)d_in[2];
  const float* spacy   = (const float*)d_in[3];
  const int*   eidx    = (const int*)d_in[4];
  const int*   batch   = (const int*)d_in[5];
  const float* Wc = (const float*)d_in[6];  const float* bc = (const float*)d_in[7];
  const float* Wb = (const float*)d_in[8];  const float* bb = (const float*)d_in[9];
  const float* Wp = (const float*)d_in[10]; const float* bp = (const float*)d_in[11];
  const float* Ws = (const float*)d_in[12]; const float* bs = (const float*)d_in[13];
  const float* Wg1 = (const float*)d_in[14]; const float* bg1 = (const float*)d_in[15];
  const float* Wg2 = (const float*)d_in[16]; const float* bg2 = (const float*)d_in[17];
  const float* Wl1 = (const float*)d_in[18]; const float* bl1 = (const float*)d_in[19];
  const float* Wl2 = (const float*)d_in[20]; const float* bl2 = (const float*)d_in[21];
  float* out = (float*)d_out;
  const int* srcp = eidx;
  const int* dstp = eidx + NE;

  const int KPC = 320, KPB = 768, KPP = 64, KPS = 320, KPG1 = 1024, KPG2 = 256;

  char* ws = (char*)d_ws;
  size_t off = 0;
  auto alloc = [&](size_t bytes) { size_t o = off; off += (bytes + 255) & ~(size_t)255; return o; };

  unsigned short* WTc  = (unsigned short*)(ws + alloc((size_t)256 * KPC * 2));
  unsigned short* WTb  = (unsigned short*)(ws + alloc((size_t)256 * KPB * 2));
  unsigned short* WTp  = (unsigned short*)(ws + alloc((size_t)256 * KPP * 2));
  unsigned short* WTs  = (unsigned short*)(ws + alloc((size_t)256 * KPS * 2));
  unsigned short* WTg1 = (unsigned short*)(ws + alloc((size_t)256 * KPG1 * 2));
  unsigned short* WTg2 = (unsigned short*)(ws + alloc((size_t)256 * KPG2 * 2));
  float* dinv    = (float*)(ws + alloc((size_t)NN * 4));
  float* selfc   = (float*)(ws + alloc((size_t)NN * 4));
  int* rowcnt    = (int*)(ws + alloc((size_t)NN * 4));
  int* rowstart  = (int*)(ws + alloc((size_t)(NN + 1) * 4));
  int* cursor    = (int*)(ws + alloc((size_t)NN * 4));
  int* csr_src   = (int*)(ws + alloc((size_t)NE * 4));
  float* csr_coef= (float*)(ws + alloc((size_t)NE * 4));
  int* bsum      = (int*)(ws + alloc(1024));
  float* pp      = (float*)(ws + alloc((size_t)POOL_BLOCKS * NGRAPH * HID * 4));
  float* cp      = (float*)(ws + alloc((size_t)POOL_BLOCKS * NGRAPH * 4));
  unsigned short* X1 = (unsigned short*)(ws + alloc((size_t)NN * 1024 * 2));   // branch concat
  unsigned short* H  = (unsigned short*)(ws + alloc((size_t)NN * 256 * 2));    // h1 / h2
  unsigned short* X2 = (unsigned short*)(ws + alloc((size_t)NN * 256 * 2));    // conv1 out
  unsigned short* X3 = (unsigned short*)(ws + alloc((size_t)NN * 256 * 2));    // conv2 out
  (void)ws_size; (void)in_sizes; (void)n_in; (void)out_size;

  hipStream_t s = stream;
  const int NB = (NN + 1023) / 1024;          // 98 scan blocks
  const int GEMM_GRID = (NN + 127) / 128;     // 782

  // weights → bf16 transposed+padded
  wconv_k<<<(256 * KPC + 255) / 256, 256, 0, s>>>(Wc, WTc, 310, KPC);
  wconv_k<<<(256 * KPB + 255) / 256, 256, 0, s>>>(Wb, WTb, 768, KPB);
  wconv_k<<<(256 * KPP + 255) / 256, 256, 0, s>>>(Wp, WTp, 10, KPP);
  wconv_k<<<(256 * KPS + 255) / 256, 256, 0, s>>>(Ws, WTs, 300, KPS);
  wconv_k<<<(256 * KPG1 + 255) / 256, 256, 0, s>>>(Wg1, WTg1, 1024, KPG1);
  wconv_k<<<(256 * KPG2 + 255) / 256, 256, 0, s>>>(Wg2, WTg2, 256, KPG2);

  // CSR build
  zero_int_k<<<(NN + 255) / 256, 256, 0, s>>>(rowcnt, NN);
  count_k<<<(NE + 255) / 256, 256, 0, s>>>(dstp, rowcnt, NE);
  deg_k<<<(NN + 255) / 256, 256, 0, s>>>(rowcnt, dinv, selfc, NN);
  scan1_k<<<NB, 256, 0, s>>>(rowcnt, bsum, NN);
  scan2_k<<<1, 256, 0, s>>>(bsum, NB);
  scan3_k<<<NB, 256, 0, s>>>(rowcnt, bsum, rowstart, cursor, NN);
  scatter_k<<<(NE + 255) / 256, 256, 0, s>>>(srcp, dstp, dinv, cursor, csr_src, csr_coef, NE);

  // branch linears + relu → X1 [N,1024] bf16
  gemm_k<true><<<GEMM_GRID, 512, 0, s>>>(content, 310, 310, KPC, WTc, bc, X1 + 0,   1024, NN, 1);
  gemm_k<true><<<GEMM_GRID, 512, 0, s>>>(bert,    768, 768, KPB, WTb, bb, X1 + 256, 1024, NN, 1);
  gemm_k<true><<<GEMM_GRID, 512, 0, s>>>(profile, 10,  10,  KPP, WTp, bp, X1 + 512, 1024, NN, 1);
  gemm_k<true><<<GEMM_GRID, 512, 0, s>>>(spacy,   300, 300, KPS, WTs, bs, X1 + 768, 1024, NN, 1);

  // conv1: h1 = X1 @ Wg1 ; agg+bias+relu → X2
  gemm_k<false><<<GEMM_GRID, 512, 0, s>>>(X1, 1024, 1024, KPG1, WTg1, nullptr, H, 256, NN, 0);
  agg_k<<<(NN + 3) / 4, 256, 0, s>>>(H, rowstart, csr_src, csr_coef, selfc, bg1, X2);

  // conv2: h2 = X2 @ Wg2 ; agg+bias+relu → X3
  gemm_k<false><<<GEMM_GRID, 512, 0, s>>>(X2, 256, 256, KPG2, WTg2, nullptr, H, 256, NN, 0);
  agg_k<<<(NN + 3) / 4, 256, 0, s>>>(H, rowstart, csr_src, csr_coef, selfc, bg2, X3);

  // pool + head
  pool_k<<<POOL_BLOCKS, 256, 0, s>>>(X3, batch, pp, cp);
  head_k<<<NGRAPH, 256, 0, s>>>(pp, cp, Wl1, bl1, Wl2, bl2, out);
}

// Round 2
// 1610.095 us; speedup vs baseline: 1.0108x; 1.0108x over previous
//
#include <hip/hip_runtime.h>
#include <hip/hip_bf16.h>
#include <stdint.h>

#define NN 100000
#define NE 1600000
#define HID 256
#define NGRAPH 64
#define POOL_BLOCKS 256

typedef __attribute__((ext_vector_type(8))) short short8;
typedef __attribute__((ext_vector_type(4))) float f32x4;
typedef __attribute__((ext_vector_type(2))) float f32x2;
typedef __attribute__((ext_vector_type(4))) unsigned int u32x4;

static __device__ inline float bf2f(unsigned short u){
  union { unsigned int i; float f; } x; x.i = ((unsigned int)u) << 16; return x.f;
}
static __device__ inline unsigned short f2bf(float f){
  union { float f; unsigned int i; } x; x.f = f;
  unsigned int r = x.i + 0x7fffu + ((x.i >> 16) & 1u);
  return (unsigned short)(r >> 16);
}
static __device__ inline void gload16(const void* g, void* l){
  __builtin_amdgcn_global_load_lds((const __attribute__((address_space(1))) void*)g,
                                   (__attribute__((address_space(3))) void*)l, 16, 0, 0);
}

struct GArgs {
  const void* A;
  const unsigned short* WT;   // [256][Kp] bf16, zero-padded
  const float* bias;          // may be null
  unsigned short* C;
  int lda, K, Kp, ldc;
};

// ---------------- GEMM v2: BM=128, BN=128, BK=32, 256 thr (4 waves 2x2),
// double-buffered LDS (2x16KB), one barrier/K-step, stage-next-overlap-compute.
// LDS swizzle: 16B chunk c at byte row*64 + ((c ^ ((row>>1)&3))<<4), both sides.
template<bool F32A, bool RELU>
__global__ __launch_bounds__(256) void gemm2_k(GArgs g0, GArgs g1, GArgs g2, GArgs g3, int M)
{
  __shared__ unsigned char smem[2][16384];  // [buf][ A:0..8K, B:8K..16K ]
  GArgs g = g0;
  if (blockIdx.z == 1) g = g1;
  else if (blockIdx.z == 2) g = g2;
  else if (blockIdx.z == 3) g = g3;

  const int tid  = threadIdx.x;
  const int lane = tid & 63;
  const int wid  = tid >> 6;        // 0..3
  const int wm   = wid >> 1;        // 0..1
  const int wn   = wid & 1;         // 0..1
  const int bm   = blockIdx.x * 128;
  const int bn   = blockIdx.y * 128;
  const int l15  = lane & 15;
  const int lk   = lane >> 4;       // 0..3
  const int K    = g.K;
  const int lda  = g.lda;
  const int Kp   = g.Kp;
  const int NK   = Kp >> 5;

  // --- per-thread staging geometry (k0-independent parts) ---
  // B tile (always bf16 via global_load_lds): 512 chunks, 2 per thread.
  int rowB[2], coB[2];
#pragma unroll
  for (int it = 0; it < 2; ++it) {
    int cidx = it * 256 + wid * 64 + lane;
    int row = cidx >> 2, ce = cidx & 3;
    rowB[it] = row;
    coB[it]  = (ce ^ ((row >> 1) & 3)) * 8;   // bf16-element offset of source chunk
  }
  // A tile bf16 path: same geometry, row clamped to M-1.
  int grA[2], coA[2];
#pragma unroll
  for (int it = 0; it < 2; ++it) {
    int cidx = it * 256 + wid * 64 + lane;
    int row = cidx >> 2, ce = cidx & 3;
    int gr = bm + row; if (gr >= M) gr = M - 1;
    grA[it] = gr;
    coA[it] = (ce ^ ((row >> 1) & 3)) * 8;
  }
  // A tile f32 path (reg-staged): chunk cidx = it*256+tid; write swizzled.
  int grF[2], kcF[2], wbF[2];
#pragma unroll
  for (int it = 0; it < 2; ++it) {
    int cidx = it * 256 + tid;
    int row = cidx >> 2, c = cidx & 3;
    int gr = bm + row; if (gr >= M) gr = M - 1;
    grF[it] = gr;
    kcF[it] = c * 8;                               // data k-offset within tile
    wbF[it] = row * 64 + ((c ^ ((row >> 1) & 3)) << 4);  // LDS byte offset
  }

  f32x4 acc[4][4];
#pragma unroll
  for (int i = 0; i < 4; i++)
#pragma unroll
    for (int j = 0; j < 4; j++) acc[i][j] = (f32x4){0.f, 0.f, 0.f, 0.f};

  const unsigned short* Ab = (const unsigned short*)g.A;
  const float* Af = (const float*)g.A;

  float fv[2][8];

  // ---- helpers as macros (static unroll) ----
#define STAGE_B(buf, k0_) do { \
  _Pragma("unroll") \
  for (int it = 0; it < 2; ++it) \
    gload16(g.WT + (size_t)(bn + rowB[it]) * Kp + (k0_) + coB[it], \
            &smem[buf][8192 + (it * 256 + wid * 64) * 16]); \
} while (0)

#define STAGE_A16(buf, k0_) do { \
  _Pragma("unroll") \
  for (int it = 0; it < 2; ++it) \
    gload16(Ab + (size_t)grA[it] * lda + (k0_) + coA[it], \
            &smem[buf][(it * 256 + wid * 64) * 16]); \
} while (0)

#define LOAD_F32(k0_) do { \
  if ((k0_) + 32 <= K) { \
    _Pragma("unroll") \
    for (int it = 0; it < 2; ++it) { \
      const float* bp = Af + (size_t)grF[it] * lda + (k0_) + kcF[it]; \
      _Pragma("unroll") \
      for (int q = 0; q < 4; ++q) { \
        f32x2 v = *(const f32x2*)(bp + 2 * q); \
        fv[it][2 * q] = v.x; fv[it][2 * q + 1] = v.y; \
      } \
    } \
  } else { \
    _Pragma("unroll") \
    for (int it = 0; it < 2; ++it) { \
      const float* bp = Af + (size_t)grF[it] * lda; \
      _Pragma("unroll") \
      for (int h = 0; h < 8; ++h) { \
        int k = (k0_) + kcF[it] + h; \
        fv[it][h] = (k < K) ? bp[k] : 0.f; \
      } \
    } \
  } \
} while (0)

#define WRITE_F32(buf) do { \
  _Pragma("unroll") \
  for (int it = 0; it < 2; ++it) { \
    u32x4 pk; \
    _Pragma("unroll") \
    for (int q = 0; q < 4; ++q) \
      pk[q] = (unsigned int)f2bf(fv[it][2 * q]) | ((unsigned int)f2bf(fv[it][2 * q + 1]) << 16); \
    *(u32x4*)(&smem[buf][wbF[it]]) = pk; \
  } \
} while (0)

  // ---- prologue: stage k-step 0 into buf 0 ----
  if (F32A) { LOAD_F32(0); WRITE_F32(0); }
  else      { STAGE_A16(0, 0); }
  STAGE_B(0, 0);
  __syncthreads();

  // ---- main loop: one barrier per K-step ----
  for (int ks = 0; ks < NK; ++ks) {
    const int cur = ks & 1;
    const int k0n = (ks + 1) << 5;
    const bool havenext = (ks + 1 < NK);
    if (havenext) {
      if (F32A) LOAD_F32(k0n);
      else      STAGE_A16(cur ^ 1, k0n);
      STAGE_B(cur ^ 1, k0n);
    }
    short8 a[4], b[4];
#pragma unroll
    for (int i = 0; i < 4; i++) {
      int row = wm * 64 + i * 16 + l15;
      a[i] = *(const short8*)(&smem[cur][row * 64 + ((lk ^ ((row >> 1) & 3)) << 4)]);
    }
#pragma unroll
    for (int j = 0; j < 4; j++) {
      int row = wn * 64 + j * 16 + l15;
      b[j] = *(const short8*)(&smem[cur][8192 + row * 64 + ((lk ^ ((row >> 1) & 3)) << 4)]);
    }
#pragma unroll
    for (int i = 0; i < 4; i++)
#pragma unroll
      for (int j = 0; j < 4; j++)
        acc[i][j] = __builtin_amdgcn_mfma_f32_16x16x32_bf16(a[i], b[j], acc[i][j], 0, 0, 0);
    if (F32A && havenext) WRITE_F32(cur ^ 1);
    __syncthreads();
  }

  // ---- epilogue ----
#pragma unroll
  for (int j = 0; j < 4; j++) {
    int col = bn + wn * 64 + j * 16 + l15;
    float bv = g.bias ? g.bias[col] : 0.f;
#pragma unroll
    for (int i = 0; i < 4; i++) {
#pragma unroll
      for (int r = 0; r < 4; r++) {
        int row = bm + wm * 64 + i * 16 + lk * 4 + r;
        if (row < M) {
          float v = acc[i][j][r] + bv;
          if (RELU) v = fmaxf(v, 0.f);
          g.C[(size_t)row * g.ldc + col] = f2bf(v);
        }
      }
    }
  }
#undef STAGE_B
#undef STAGE_A16
#undef LOAD_F32
#undef WRITE_F32
}

// ---------------- weight transpose + pad + bf16 convert ----------------
__global__ void wconv_k(const float* __restrict__ W, unsigned short* __restrict__ WT,
                        int K, int Kp)
{
  int idx = blockIdx.x * 256 + threadIdx.x;
  if (idx >= 256 * Kp) return;
  int n = idx / Kp, k = idx - n * Kp;
  float v = (k < K) ? W[(size_t)k * 256 + n] : 0.f;
  WT[(size_t)n * Kp + k] = f2bf(v);
}

// ---------------- CSR build ----------------
__global__ void zero_int_k(int* p, int n){
  int i = blockIdx.x * 256 + threadIdx.x; if (i < n) p[i] = 0;
}
__global__ void count_k(const int* __restrict__ dst, int* __restrict__ cnt, int n){
  int e = blockIdx.x * 256 + threadIdx.x; if (e < n) atomicAdd(&cnt[dst[e]], 1);
}
__global__ void deg_k(const int* __restrict__ cnt, float* __restrict__ dinv,
                      float* __restrict__ selfc, int n){
  int i = blockIdx.x * 256 + threadIdx.x;
  if (i < n) { float d = 1.0f + (float)cnt[i]; dinv[i] = rsqrtf(d); selfc[i] = 1.0f / d; }
}
__global__ void scan1_k(const int* __restrict__ cnt, int* __restrict__ bsum, int n){
  __shared__ int s[256];
  int b = blockIdx.x, t = threadIdx.x;
  int base = b * 1024 + t * 4, v = 0;
#pragma unroll
  for (int j = 0; j < 4; j++) { int i = base + j; if (i < n) v += cnt[i]; }
  s[t] = v; __syncthreads();
  for (int o = 128; o > 0; o >>= 1) { if (t < o) s[t] += s[t + o]; __syncthreads(); }
  if (t == 0) bsum[b] = s[0];
}
__global__ void scan2_k(int* bsum, int nb){
  __shared__ int s[256];
  int t = threadIdx.x;
  int v = (t < nb) ? bsum[t] : 0;
  s[t] = v; __syncthreads();
  for (int o = 1; o < 256; o <<= 1) {
    int x = (t >= o) ? s[t - o] : 0; __syncthreads();
    s[t] += x; __syncthreads();
  }
  if (t < nb) bsum[t] = s[t] - v;   // exclusive
}
__global__ void scan3_k(const int* __restrict__ cnt, const int* __restrict__ bsum,
                        int* __restrict__ rowstart, int* __restrict__ cursor, int n){
  __shared__ int s[256];
  int b = blockIdx.x, t = threadIdx.x;
  int base = b * 1024 + t * 4;
  int c0 = 0, c1 = 0, c2 = 0, c3 = 0;
  if (base + 0 < n) c0 = cnt[base + 0];
  if (base + 1 < n) c1 = cnt[base + 1];
  if (base + 2 < n) c2 = cnt[base + 2];
  if (base + 3 < n) c3 = cnt[base + 3];
  int ts = c0 + c1 + c2 + c3;
  s[t] = ts; __syncthreads();
  for (int o = 1; o < 256; o <<= 1) {
    int x = (t >= o) ? s[t - o] : 0; __syncthreads();
    s[t] += x; __syncthreads();
  }
  int run = bsum[b] + s[t] - ts;
  int cc[4] = {c0, c1, c2, c3};
#pragma unroll
  for (int j = 0; j < 4; j++) {
    int i = base + j;
    if (i < n) {
      rowstart[i] = run; cursor[i] = run; run += cc[j];
      if (i == n - 1) rowstart[n] = run;
    }
  }
}
__global__ void scatter_k(const int* __restrict__ src, const int* __restrict__ dst,
                          const float* __restrict__ dinv, int* __restrict__ cursor,
                          int* __restrict__ csr_src, float* __restrict__ csr_coef, int n){
  int e = blockIdx.x * 256 + threadIdx.x; if (e >= n) return;
  int d = dst[e], s = src[e];
  int p = atomicAdd(&cursor[d], 1);
  csr_src[p] = s;
  csr_coef[p] = dinv[s] * dinv[d];
}

// ---------------- aggregation: out = relu(sum coef*h[src] + selfc*h[dst] + b) ---
__global__ __launch_bounds__(256) void agg_k(
    const unsigned short* __restrict__ h,
    const int* __restrict__ rowstart, const int* __restrict__ csr_src,
    const float* __restrict__ csr_coef, const float* __restrict__ selfc,
    const float* __restrict__ bias, unsigned short* __restrict__ out)
{
  int dst = blockIdx.x * 4 + (threadIdx.x >> 6);
  if (dst >= NN) return;
  int lane = threadIdx.x & 63;
  int colb = lane * 4;
  const unsigned short* hb = h + colb;
  ushort4 hv = *(const ushort4*)(hb + (size_t)dst * 256);
  float sc = selfc[dst];
  float a0 = sc * bf2f(hv.x), a1 = sc * bf2f(hv.y), a2 = sc * bf2f(hv.z), a3 = sc * bf2f(hv.w);
  int e0 = rowstart[dst], e1 = rowstart[dst + 1];
  int e = e0;
  for (; e + 4 <= e1; e += 4) {
    int s0 = csr_src[e], s1 = csr_src[e + 1], s2 = csr_src[e + 2], s3 = csr_src[e + 3];
    float c0 = csr_coef[e], c1 = csr_coef[e + 1], c2 = csr_coef[e + 2], c3 = csr_coef[e + 3];
    ushort4 v0 = *(const ushort4*)(hb + (size_t)s0 * 256);
    ushort4 v1 = *(const ushort4*)(hb + (size_t)s1 * 256);
    ushort4 v2 = *(const ushort4*)(hb + (size_t)s2 * 256);
    ushort4 v3 = *(const ushort4*)(hb + (size_t)s3 * 256);
    a0 += c0 * bf2f(v0.x) + c1 * bf2f(v1.x) + c2 * bf2f(v2.x) + c3 * bf2f(v3.x);
    a1 += c0 * bf2f(v0.y) + c1 * bf2f(v1.y) + c2 * bf2f(v2.y) + c3 * bf2f(v3.y);
    a2 += c0 * bf2f(v0.z) + c1 * bf2f(v1.z) + c2 * bf2f(v2.z) + c3 * bf2f(v3.z);
    a3 += c0 * bf2f(v0.w) + c1 * bf2f(v1.w) + c2 * bf2f(v2.w) + c3 * bf2f(v3.w);
  }
  for (; e < e1; ++e) {
    int s0 = csr_src[e]; float c0 = csr_coef[e];
    ushort4 v0 = *(const ushort4*)(hb + (size_t)s0 * 256);
    a0 += c0 * bf2f(v0.x); a1 += c0 * bf2f(v0.y); a2 += c0 * bf2f(v0.z); a3 += c0 * bf2f(v0.w);
  }
  float4 bv = *(const float4*)(bias + colb);
  a0 = fmaxf(a0 + bv.x, 0.f); a1 = fmaxf(a1 + bv.y, 0.f);
  a2 = fmaxf(a2 + bv.z, 0.f); a3 = fmaxf(a3 + bv.w, 0.f);
  ushort4 o; o.x = f2bf(a0); o.y = f2bf(a1); o.z = f2bf(a2); o.w = f2bf(a3);
  *(ushort4*)(out + (size_t)dst * 256 + colb) = o;
}

// ---------------- pooling partials ----------------
__global__ __launch_bounds__(256) void pool_k(
    const unsigned short* __restrict__ x, const int* __restrict__ batch,
    float* __restrict__ pp, float* __restrict__ cp)
{
  __shared__ float acc[NGRAPH][HID];   // 64KB
  __shared__ float cl[NGRAPH];
  int t = threadIdx.x, b = blockIdx.x;
  for (int i = t; i < NGRAPH * HID; i += 256) ((float*)acc)[i] = 0.f;
  if (t < NGRAPH) cl[t] = 0.f;
  __syncthreads();
  int per = (NN + POOL_BLOCKS - 1) / POOL_BLOCKS;
  int i0 = b * per, i1 = min(NN, i0 + per);
  for (int i = i0; i < i1; ++i) {
    int g = batch[i];
    acc[g][t] += bf2f(x[(size_t)i * 256 + t]);
    if (t == 0) cl[g] += 1.f;
  }
  __syncthreads();
  for (int g = 0; g < NGRAPH; ++g) pp[(size_t)b * (NGRAPH * HID) + g * HID + t] = acc[g][t];
  if (t < NGRAPH) cp[b * NGRAPH + t] = cl[t];
}

// ---------------- head ----------------
__global__ __launch_bounds__(256) void head_k(
    const float* __restrict__ pp, const float* __restrict__ cp,
    const float* __restrict__ Wl1, const float* __restrict__ bl1,
    const float* __restrict__ Wl2, const float* __restrict__ bl2,
    float* __restrict__ out)
{
  __shared__ float pooled[HID];
  __shared__ float red[2][4];
  int g = blockIdx.x, t = threadIdx.x;
  float s = 0.f;
  for (int b = 0; b < POOL_BLOCKS; ++b) s += pp[(size_t)b * (NGRAPH * HID) + g * HID + t];
  float cnt = 0.f;
  for (int b = 0; b < POOL_BLOCKS; ++b) cnt += cp[b * NGRAPH + g];
  pooled[t] = s / fmaxf(cnt, 1.f);
  __syncthreads();
  float hv = bl1[t];
  for (int k = 0; k < HID; ++k) hv += pooled[k] * Wl1[k * HID + t];
  hv = fmaxf(hv, 0.f);
  float p0 = hv * Wl2[t * 2 + 0];
  float p1 = hv * Wl2[t * 2 + 1];
  for (int o = 32; o > 0; o >>= 1) { p0 += __shfl_down(p0, o); p1 += __shfl_down(p1, o); }
  int w = t >> 6;
  if ((t & 63) == 0) { red[0][w] = p0; red[1][w] = p1; }
  __syncthreads();
  if (t == 0) {
    float l0 = bl2[0], l1 = bl2[1];
#pragma unroll
    for (int i = 0; i < 4; i++) { l0 += red[0][i]; l1 += red[1][i]; }
    float m = fmaxf(l0, l1);
    float lse = m + logf(expf(l0 - m) + expf(l1 - m));
    out[g * 2 + 0] = l0 - lse;
    out[g * 2 + 1] = l1 - lse;
  }
}

// ---------------- launch ----------------
extern "C" void kernel_launch(void* const* d_in, const int* in_sizes, int n_in,
                              void* d_out, int out_size, void* d_ws, size_t ws_size,
                              hipStream_t stream)
{
  const float* content = (const float*)d_in[0];
  const float* bert    = (const float*)d_in[1];
  const float* profile = (const float*)d_in[2];
  const float* spacy   = (const float*)d_in[3];
  const int*   eidx    = (const int*)d_in[4];
  const int*   batch   = (const int*)d_in[5];
  const float* Wc = (const float*)d_in[6];  const float* bc = (const float*)d_in[7];
  const float* Wb = (const float*)d_in[8];  const float* bb = (const float*)d_in[9];
  const float* Wp = (const float*)d_in[10]; const float* bp = (const float*)d_in[11];
  const float* Ws = (const float*)d_in[12]; const float* bs = (const float*)d_in[13];
  const float* Wg1 = (const float*)d_in[14]; const float* bg1 = (const float*)d_in[15];
  const float* Wg2 = (const float*)d_in[16]; const float* bg2 = (const float*)d_in[17];
  const float* Wl1 = (const float*)d_in[18]; const float* bl1 = (const float*)d_in[19];
  const float* Wl2 = (const float*)d_in[20]; const float* bl2 = (const float*)d_in[21];
  float* out = (float*)d_out;
  const int* srcp = eidx;
  const int* dstp = eidx + NE;

  const int KPC = 320, KPB = 768, KPP = 32, KPS = 320, KPG1 = 1024, KPG2 = 256;

  char* ws = (char*)d_ws;
  size_t off = 0;
  auto alloc = [&](size_t bytes) { size_t o = off; off += (bytes + 255) & ~(size_t)255; return o; };

  unsigned short* WTc  = (unsigned short*)(ws + alloc((size_t)256 * KPC * 2));
  unsigned short* WTb  = (unsigned short*)(ws + alloc((size_t)256 * KPB * 2));
  unsigned short* WTp  = (unsigned short*)(ws + alloc((size_t)256 * KPP * 2));
  unsigned short* WTs  = (unsigned short*)(ws + alloc((size_t)256 * KPS * 2));
  unsigned short* WTg1 = (unsigned short*)(ws + alloc((size_t)256 * KPG1 * 2));
  unsigned short* WTg2 = (unsigned short*)(ws + alloc((size_t)256 * KPG2 * 2));
  float* dinv    = (float*)(ws + alloc((size_t)NN * 4));
  float* selfc   = (float*)(ws + alloc((size_t)NN * 4));
  int* rowcnt    = (int*)(ws + alloc((size_t)NN * 4));
  int* rowstart  = (int*)(ws + alloc((size_t)(NN + 1) * 4));
  int* cursor    = (int*)(ws + alloc((size_t)NN * 4));
  int* csr_src   = (int*)(ws + alloc((size_t)NE * 4));
  float* csr_coef= (float*)(ws + alloc((size_t)NE * 4));
  int* bsum      = (int*)(ws + alloc(1024));
  float* pp      = (float*)(ws + alloc((size_t)POOL_BLOCKS * NGRAPH * HID * 4));
  float* cp      = (float*)(ws + alloc((size_t)POOL_BLOCKS * NGRAPH * 4));
  unsigned short* X1 = (unsigned short*)(ws + alloc((size_t)NN * 1024 * 2));
  unsigned short* H  = (unsigned short*)(ws + alloc((size_t)NN * 256 * 2));
  unsigned short* X2 = (unsigned short*)(ws + alloc((size_t)NN * 256 * 2));
  unsigned short* X3 = (unsigned short*)(ws + alloc((size_t)NN * 256 * 2));
  (void)ws_size; (void)in_sizes; (void)n_in; (void)out_size;

  hipStream_t s = stream;
  const int NB = (NN + 1023) / 1024;
  const int MB = (NN + 127) / 128;    // 782

  wconv_k<<<(256 * KPC + 255) / 256, 256, 0, s>>>(Wc, WTc, 310, KPC);
  wconv_k<<<(256 * KPB + 255) / 256, 256, 0, s>>>(Wb, WTb, 768, KPB);
  wconv_k<<<(256 * KPP + 255) / 256, 256, 0, s>>>(Wp, WTp, 10, KPP);
  wconv_k<<<(256 * KPS + 255) / 256, 256, 0, s>>>(Ws, WTs, 300, KPS);
  wconv_k<<<(256 * KPG1 + 255) / 256, 256, 0, s>>>(Wg1, WTg1, 1024, KPG1);
  wconv_k<<<(256 * KPG2 + 255) / 256, 256, 0, s>>>(Wg2, WTg2, 256, KPG2);

  zero_int_k<<<(NN + 255) / 256, 256, 0, s>>>(rowcnt, NN);
  count_k<<<(NE + 255) / 256, 256, 0, s>>>(dstp, rowcnt, NE);
  deg_k<<<(NN + 255) / 256, 256, 0, s>>>(rowcnt, dinv, selfc, NN);
  scan1_k<<<NB, 256, 0, s>>>(rowcnt, bsum, NN);
  scan2_k<<<1, 256, 0, s>>>(bsum, NB);
  scan3_k<<<NB, 256, 0, s>>>(rowcnt, bsum, rowstart, cursor, NN);
  scatter_k<<<(NE + 255) / 256, 256, 0, s>>>(srcp, dstp, dinv, cursor, csr_src, csr_coef, NE);

  // fused branch linears + relu -> X1 [N,1024] bf16  (gridDim.z = branch)
  {
    GArgs gc = { content, WTc, bc, X1 + 0,   310, 310, KPC, 1024 };
    GArgs gb = { bert,    WTb, bb, X1 + 256, 768, 768, KPB, 1024 };
    GArgs gp = { profile, WTp, bp, X1 + 512, 10,  10,  KPP, 1024 };
    GArgs gs = { spacy,   WTs, bs, X1 + 768, 300, 300, KPS, 1024 };
    gemm2_k<true, true><<<dim3(MB, 2, 4), 256, 0, s>>>(gc, gb, gp, gs, NN);
  }

  // conv1: H = X1 @ Wg1 ; agg+bias+relu -> X2
  {
    GArgs g1 = { X1, WTg1, nullptr, H, 1024, 1024, KPG1, 256 };
    gemm2_k<false, false><<<dim3(MB, 2, 1), 256, 0, s>>>(g1, g1, g1, g1, NN);
  }
  agg_k<<<(NN + 3) / 4, 256, 0, s>>>(H, rowstart, csr_src, csr_coef, selfc, bg1, X2);

  // conv2: H = X2 @ Wg2 ; agg+bias+relu -> X3
  {
    GArgs g2 = { X2, WTg2, nullptr, H, 256, 256, KPG2, 256 };
    gemm2_k<false, false><<<dim3(MB, 2, 1), 256, 0, s>>>(g2, g2, g2, g2, NN);
  }
  agg_k<<<(NN + 3) / 4, 256, 0, s>>>(H, rowstart, csr_src, csr_coef, selfc, bg2, X3);

  pool_k<<<POOL_BLOCKS, 256, 0, s>>>(X3, batch, pp, cp);
  head_k<<<NGRAPH, 256, 0, s>>>(pp, cp, Wl1, bl1, Wl2, bl2, out);
}

// Round 3
// 1543.633 us; speedup vs baseline: 1.0543x; 1.0431x over previous
//
#include <hip/hip_runtime.h>
#include <hip/hip_bf16.h>
#include <stdint.h>

#define NN 100000
#define NE 1600000
#define HID 256
#define NGRAPH 64
#define POOL_BLOCKS 256

typedef __attribute__((ext_vector_type(8))) short short8;
typedef __attribute__((ext_vector_type(4))) float f32x4;
typedef __attribute__((ext_vector_type(4))) unsigned int u32x4;

static __device__ inline float bf2f(unsigned short u){
  union { unsigned int i; float f; } x; x.i = ((unsigned int)u) << 16; return x.f;
}
static __device__ inline unsigned short f2bf(float f){
  union { float f; unsigned int i; } x; x.f = f;
  unsigned int r = x.i + 0x7fffu + ((x.i >> 16) & 1u);
  return (unsigned short)(r >> 16);
}
static __device__ inline void gload16(const void* g, void* l){
  __builtin_amdgcn_global_load_lds((const __attribute__((address_space(1))) void*)g,
                                   (__attribute__((address_space(3))) void*)l, 16, 0, 0);
}
// counted-vmcnt fences + raw barrier (T4): keep prefetched loads in flight across barriers
static __device__ __forceinline__ void fence_bar_v8(){
  asm volatile("s_waitcnt vmcnt(8) lgkmcnt(0)" ::: "memory");
  __builtin_amdgcn_s_barrier(); __builtin_amdgcn_sched_barrier(0);
}
static __device__ __forceinline__ void fence_bar_v4(){
  asm volatile("s_waitcnt vmcnt(4) lgkmcnt(0)" ::: "memory");
  __builtin_amdgcn_s_barrier(); __builtin_amdgcn_sched_barrier(0);
}
static __device__ __forceinline__ void fence_bar_v0(){
  asm volatile("s_waitcnt vmcnt(0) lgkmcnt(0)" ::: "memory");
  __builtin_amdgcn_s_barrier(); __builtin_amdgcn_sched_barrier(0);
}

struct GArgs {
  const void* A;
  const unsigned short* WT;   // [256][Kp] bf16, zero-padded
  const float* bias;
  unsigned short* C;
  int lda, K, Kp, ldc;
};

// ================= branch GEMM: f32 A, 2-buf LDS, 2-deep reg prefetch =========
// block 128x128, 4 waves (2x2), wave 64x64, BK=32. relu+bias fused.
__global__ __launch_bounds__(256) void gemmf_k(GArgs g0, GArgs g1, GArgs g2, GArgs g3, int M)
{
  __shared__ unsigned char smem[2][16384];   // per buf: A [0,8K), B [8K,16K)
  GArgs g = g0;
  if (blockIdx.z == 1) g = g1;
  else if (blockIdx.z == 2) g = g2;
  else if (blockIdx.z == 3) g = g3;

  const int tid = threadIdx.x, lane = tid & 63, wid = tid >> 6;
  const int wm = wid >> 1, wn = wid & 1;
  const int bm = blockIdx.x * 128, bn = blockIdx.y * 128;
  const int l15 = lane & 15, lk = lane >> 4;
  const int K = g.K, Kp = g.Kp, lda = g.lda, NK = Kp >> 5;
  const float* Af = (const float*)g.A;

  // A f32 staging geometry (2 chunks of 32B per thread)
  size_t rbF[2]; int kcF[2], wbF[2];
#pragma unroll
  for (int it = 0; it < 2; ++it) {
    int cidx = it * 256 + tid, row = cidx >> 2, c = cidx & 3;
    int gr = bm + row; if (gr >= M) gr = M - 1;
    rbF[it] = (size_t)gr * lda; kcF[it] = c * 8;
    wbF[it] = row * 64 + ((c ^ ((row >> 1) & 3)) << 4);
  }
  // B staging geometry (2 gload16 per thread)
  size_t obB[2]; int ldsB[2];
#pragma unroll
  for (int it = 0; it < 2; ++it) {
    int inst = it * 4 + wid, cidx = inst * 64 + lane, row = cidx >> 2, c = cidx & 3;
    obB[it] = (size_t)(bn + row) * Kp + (c ^ ((row >> 1) & 3)) * 8;
    ldsB[it] = 8192 + inst * 1024;
  }

  float2 fvA[8], fvB[8];
  f32x4 acc[4][4];
#pragma unroll
  for (int i = 0; i < 4; i++)
#pragma unroll
    for (int j = 0; j < 4; j++) acc[i][j] = (f32x4){0.f, 0.f, 0.f, 0.f};

#define LOADF(S, k0_) do{ \
  if ((k0_) + 32 <= K) { \
    _Pragma("unroll") for (int it = 0; it < 2; ++it){ \
      const float* bp = Af + rbF[it] + (k0_) + kcF[it]; \
      _Pragma("unroll") for (int q = 0; q < 4; ++q) S[it*4+q] = *(const float2*)(bp + 2*q); \
    } \
  } else { \
    _Pragma("unroll") for (int it = 0; it < 2; ++it){ \
      const float* bp = Af + rbF[it]; \
      _Pragma("unroll") for (int q = 0; q < 4; ++q){ \
        int k = (k0_) + kcF[it] + 2*q; \
        S[it*4+q].x = (k < K) ? bp[k] : 0.f; \
        S[it*4+q].y = (k+1 < K) ? bp[k+1] : 0.f; \
      } } } } while(0)

#define CVTW(S, bufb) do{ \
  _Pragma("unroll") for (int it = 0; it < 2; ++it){ \
    u32x4 pk; \
    _Pragma("unroll") for (int q = 0; q < 4; ++q) \
      pk[q] = (unsigned)f2bf(S[it*4+q].x) | ((unsigned)f2bf(S[it*4+q].y) << 16); \
    *(u32x4*)(&smem[bufb][wbF[it]]) = pk; } } while(0)

#define STAGEB(bufb, k0_) do{ \
  _Pragma("unroll") for (int it = 0; it < 2; ++it) \
    gload16(g.WT + obB[it] + (k0_), &smem[bufb][ldsB[it]]); } while(0)

#define DOMFMA(bufb) do{ \
  short8 a[4], b[4]; \
  _Pragma("unroll") for (int i = 0; i < 4; ++i){ int row = wm*64 + i*16 + l15; \
    a[i] = *(const short8*)(&smem[bufb][row*64 + ((lk ^ ((row>>1)&3)) << 4)]); } \
  _Pragma("unroll") for (int j = 0; j < 4; ++j){ int row = wn*64 + j*16 + l15; \
    b[j] = *(const short8*)(&smem[bufb][8192 + row*64 + ((lk ^ ((row>>1)&3)) << 4)]); } \
  _Pragma("unroll") for (int i = 0; i < 4; ++i) \
    _Pragma("unroll") for (int j = 0; j < 4; ++j) \
      acc[i][j] = __builtin_amdgcn_mfma_f32_16x16x32_bf16(a[i], b[j], acc[i][j], 0, 0, 0); \
  } while(0)

  // prologue: tile0 -> buf0 (full wait), A-regs for tile1
  LOADF(fvA, 0);
  CVTW(fvA, 0);
  STAGEB(0, 0);
  LOADF(fvB, 32);               // NK >= 2 always (all Kp multiples of 64)
  fence_bar_v8();               // retire B(T0); keep fvB(T1) in flight

  for (int t = 0; t < NK; t += 2) {
    { const bool h1 = (t + 1) < NK, h2 = (t + 2) < NK;
      if (h1) STAGEB(1, (t + 1) << 5);
      if (h2) LOADF(fvA, (t + 2) << 5);
      DOMFMA(0);
      if (h1) CVTW(fvB, 1);
      if (h2) fence_bar_v8(); else fence_bar_v0(); }
    { const bool h1 = (t + 2) < NK, h2 = (t + 3) < NK;
      if (h1) STAGEB(0, (t + 2) << 5);
      if (h2) LOADF(fvB, (t + 3) << 5);
      DOMFMA(1);
      if (h1) CVTW(fvA, 0);
      if (h2) fence_bar_v8(); else fence_bar_v0(); }
  }

  // epilogue: bias+relu, shfl-pack col pairs -> 4B stores
#pragma unroll
  for (int j = 0; j < 4; j++) {
    int col = bn + wn * 64 + j * 16 + l15;
    float bv = g.bias[col];
#pragma unroll
    for (int i = 0; i < 4; i++) {
#pragma unroll
      for (int r = 0; r < 4; r++) {
        int row = bm + wm * 64 + i * 16 + lk * 4 + r;
        float v = fmaxf(acc[i][j][r] + bv, 0.f);
        unsigned u = f2bf(v);
        unsigned pu = (unsigned)__shfl_xor((int)u, 1);
        if (!(lane & 1) && row < M)
          *(unsigned*)(g.C + (size_t)row * g.ldc + col) = u | (pu << 16);
      }
    }
  }
#undef LOADF
#undef CVTW
#undef STAGEB
#undef DOMFMA
}

// ================= conv GEMM: bf16 A, 3-buf LDS ring, 2-tile-deep gload =======
// block 128x128, 4 waves (2x2), wave 64x64, BK=32. No bias/relu (agg applies).
__global__ __launch_bounds__(256) void gemmb_k(GArgs g, int M)
{
  __shared__ unsigned char smem[49152];      // 3 bufs x (A 8K + B 8K)
  const int tid = threadIdx.x, lane = tid & 63, wid = tid >> 6;
  const int wm = wid >> 1, wn = wid & 1;
  const int bm = blockIdx.x * 128, bn = blockIdx.y * 128;
  const int l15 = lane & 15, lk = lane >> 4;
  const int Kp = g.Kp, lda = g.lda, NK = Kp >> 5;
  const unsigned short* Ab = (const unsigned short*)g.A;

  size_t obA[2], obB[2]; int ldsA[2], ldsB[2];
#pragma unroll
  for (int it = 0; it < 2; ++it) {
    int inst = it * 4 + wid, cidx = inst * 64 + lane, row = cidx >> 2, c = cidx & 3;
    int gr = bm + row; if (gr >= M) gr = M - 1;
    obA[it] = (size_t)gr * lda + (c ^ ((row >> 1) & 3)) * 8;
    ldsA[it] = inst * 1024;
    obB[it] = (size_t)(bn + row) * Kp + (c ^ ((row >> 1) & 3)) * 8;
    ldsB[it] = 8192 + inst * 1024;
  }

  f32x4 acc[4][4];
#pragma unroll
  for (int i = 0; i < 4; i++)
#pragma unroll
    for (int j = 0; j < 4; j++) acc[i][j] = (f32x4){0.f, 0.f, 0.f, 0.f};

#define STAGE3(ob_, k0_) do{ \
  _Pragma("unroll") for (int it = 0; it < 2; ++it) \
    gload16(Ab + obA[it] + (k0_), smem + (ob_) + ldsA[it]); \
  _Pragma("unroll") for (int it = 0; it < 2; ++it) \
    gload16(g.WT + obB[it] + (k0_), smem + (ob_) + ldsB[it]); } while(0)

  STAGE3(0, 0);
  STAGE3(16384, 32);
  fence_bar_v4();               // retire tile0; tile1 stays in flight
  int o0 = 0, o1 = 16384, o2 = 32768;

  for (int t = 0; t < NK; ++t) {
    const bool h2 = (t + 2) < NK;
    if (h2) STAGE3(o2, (t + 2) << 5);
    short8 a[4], b[4];
#pragma unroll
    for (int i = 0; i < 4; ++i) { int row = wm * 64 + i * 16 + l15;
      a[i] = *(const short8*)(smem + o0 + row * 64 + ((lk ^ ((row >> 1) & 3)) << 4)); }
#pragma unroll
    for (int j = 0; j < 4; ++j) { int row = wn * 64 + j * 16 + l15;
      b[j] = *(const short8*)(smem + o0 + 8192 + row * 64 + ((lk ^ ((row >> 1) & 3)) << 4)); }
#pragma unroll
    for (int i = 0; i < 4; ++i)
#pragma unroll
      for (int j = 0; j < 4; ++j)
        acc[i][j] = __builtin_amdgcn_mfma_f32_16x16x32_bf16(a[i], b[j], acc[i][j], 0, 0, 0);
    if (h2) fence_bar_v4(); else fence_bar_v0();
    int tmp = o0; o0 = o1; o1 = o2; o2 = tmp;
  }

#pragma unroll
  for (int j = 0; j < 4; j++) {
    int col = bn + wn * 64 + j * 16 + l15;
#pragma unroll
    for (int i = 0; i < 4; i++) {
#pragma unroll
      for (int r = 0; r < 4; r++) {
        int row = bm + wm * 64 + i * 16 + lk * 4 + r;
        unsigned u = f2bf(acc[i][j][r]);
        unsigned pu = (unsigned)__shfl_xor((int)u, 1);
        if (!(lane & 1) && row < M)
          *(unsigned*)(g.C + (size_t)row * g.ldc + col) = u | (pu << 16);
      }
    }
  }
#undef STAGE3
}

// ---------------- weight transpose + pad + bf16 convert ----------------
__global__ void wconv_k(const float* __restrict__ W, unsigned short* __restrict__ WT,
                        int K, int Kp)
{
  int idx = blockIdx.x * 256 + threadIdx.x;
  if (idx >= 256 * Kp) return;
  int n = idx / Kp, k = idx - n * Kp;
  float v = (k < K) ? W[(size_t)k * 256 + n] : 0.f;
  WT[(size_t)n * Kp + k] = f2bf(v);
}

// ---------------- CSR build ----------------
__global__ void zero_int_k(int* p, int n){
  int i = blockIdx.x * 256 + threadIdx.x; if (i < n) p[i] = 0;
}
__global__ void count_k(const int* __restrict__ dst, int* __restrict__ cnt, int n){
  int e = blockIdx.x * 256 + threadIdx.x; if (e < n) atomicAdd(&cnt[dst[e]], 1);
}
__global__ void deg_k(const int* __restrict__ cnt, float* __restrict__ dinv,
                      float* __restrict__ selfc, int n){
  int i = blockIdx.x * 256 + threadIdx.x;
  if (i < n) { float d = 1.0f + (float)cnt[i]; dinv[i] = rsqrtf(d); selfc[i] = 1.0f / d; }
}
__global__ void scan1_k(const int* __restrict__ cnt, int* __restrict__ bsum, int n){
  __shared__ int s[256];
  int b = blockIdx.x, t = threadIdx.x;
  int base = b * 1024 + t * 4, v = 0;
#pragma unroll
  for (int j = 0; j < 4; j++) { int i = base + j; if (i < n) v += cnt[i]; }
  s[t] = v; __syncthreads();
  for (int o = 128; o > 0; o >>= 1) { if (t < o) s[t] += s[t + o]; __syncthreads(); }
  if (t == 0) bsum[b] = s[0];
}
__global__ void scan2_k(int* bsum, int nb){
  __shared__ int s[256];
  int t = threadIdx.x;
  int v = (t < nb) ? bsum[t] : 0;
  s[t] = v; __syncthreads();
  for (int o = 1; o < 256; o <<= 1) {
    int x = (t >= o) ? s[t - o] : 0; __syncthreads();
    s[t] += x; __syncthreads();
  }
  if (t < nb) bsum[t] = s[t] - v;
}
__global__ void scan3_k(const int* __restrict__ cnt, const int* __restrict__ bsum,
                        int* __restrict__ rowstart, int* __restrict__ cursor, int n){
  __shared__ int s[256];
  int b = blockIdx.x, t = threadIdx.x;
  int base = b * 1024 + t * 4;
  int c0 = 0, c1 = 0, c2 = 0, c3 = 0;
  if (base + 0 < n) c0 = cnt[base + 0];
  if (base + 1 < n) c1 = cnt[base + 1];
  if (base + 2 < n) c2 = cnt[base + 2];
  if (base + 3 < n) c3 = cnt[base + 3];
  int ts = c0 + c1 + c2 + c3;
  s[t] = ts; __syncthreads();
  for (int o = 1; o < 256; o <<= 1) {
    int x = (t >= o) ? s[t - o] : 0; __syncthreads();
    s[t] += x; __syncthreads();
  }
  int run = bsum[b] + s[t] - ts;
  int cc[4] = {c0, c1, c2, c3};
#pragma unroll
  for (int j = 0; j < 4; j++) {
    int i = base + j;
    if (i < n) {
      rowstart[i] = run; cursor[i] = run; run += cc[j];
      if (i == n - 1) rowstart[n] = run;
    }
  }
}
__global__ void scatter_k(const int* __restrict__ src, const int* __restrict__ dst,
                          const float* __restrict__ dinv, int* __restrict__ cursor,
                          int* __restrict__ csr_src, float* __restrict__ csr_coef, int n){
  int e = blockIdx.x * 256 + threadIdx.x; if (e >= n) return;
  int d = dst[e], s = src[e];
  int p = atomicAdd(&cursor[d], 1);
  csr_src[p] = s;
  csr_coef[p] = dinv[s] * dinv[d];
}

// ---------------- aggregation ----------------
__global__ __launch_bounds__(256) void agg_k(
    const unsigned short* __restrict__ h,
    const int* __restrict__ rowstart, const int* __restrict__ csr_src,
    const float* __restrict__ csr_coef, const float* __restrict__ selfc,
    const float* __restrict__ bias, unsigned short* __restrict__ out)
{
  int dst = blockIdx.x * 4 + (threadIdx.x >> 6);
  if (dst >= NN) return;
  int lane = threadIdx.x & 63;
  int colb = lane * 4;
  const unsigned short* hb = h + colb;
  ushort4 hv = *(const ushort4*)(hb + (size_t)dst * 256);
  float sc = selfc[dst];
  float a0 = sc * bf2f(hv.x), a1 = sc * bf2f(hv.y), a2 = sc * bf2f(hv.z), a3 = sc * bf2f(hv.w);
  int e0 = rowstart[dst], e1 = rowstart[dst + 1];
  int e = e0;
  for (; e + 8 <= e1; e += 8) {
    int ss[8]; float cc[8]; ushort4 vv[8];
#pragma unroll
    for (int q = 0; q < 8; ++q) { ss[q] = csr_src[e + q]; cc[q] = csr_coef[e + q]; }
#pragma unroll
    for (int q = 0; q < 8; ++q) vv[q] = *(const ushort4*)(hb + (size_t)ss[q] * 256);
#pragma unroll
    for (int q = 0; q < 8; ++q) {
      a0 += cc[q] * bf2f(vv[q].x); a1 += cc[q] * bf2f(vv[q].y);
      a2 += cc[q] * bf2f(vv[q].z); a3 += cc[q] * bf2f(vv[q].w);
    }
  }
  for (; e + 2 <= e1; e += 2) {
    int s0 = csr_src[e], s1 = csr_src[e + 1];
    float c0 = csr_coef[e], c1 = csr_coef[e + 1];
    ushort4 v0 = *(const ushort4*)(hb + (size_t)s0 * 256);
    ushort4 v1 = *(const ushort4*)(hb + (size_t)s1 * 256);
    a0 += c0 * bf2f(v0.x) + c1 * bf2f(v1.x); a1 += c0 * bf2f(v0.y) + c1 * bf2f(v1.y);
    a2 += c0 * bf2f(v0.z) + c1 * bf2f(v1.z); a3 += c0 * bf2f(v0.w) + c1 * bf2f(v1.w);
  }
  if (e < e1) {
    int s0 = csr_src[e]; float c0 = csr_coef[e];
    ushort4 v0 = *(const ushort4*)(hb + (size_t)s0 * 256);
    a0 += c0 * bf2f(v0.x); a1 += c0 * bf2f(v0.y); a2 += c0 * bf2f(v0.z); a3 += c0 * bf2f(v0.w);
  }
  float4 bv = *(const float4*)(bias + colb);
  a0 = fmaxf(a0 + bv.x, 0.f); a1 = fmaxf(a1 + bv.y, 0.f);
  a2 = fmaxf(a2 + bv.z, 0.f); a3 = fmaxf(a3 + bv.w, 0.f);
  ushort4 o; o.x = f2bf(a0); o.y = f2bf(a1); o.z = f2bf(a2); o.w = f2bf(a3);
  *(ushort4*)(out + (size_t)dst * 256 + colb) = o;
}

// ---------------- pooling partials ----------------
__global__ __launch_bounds__(256) void pool_k(
    const unsigned short* __restrict__ x, const int* __restrict__ batch,
    float* __restrict__ pp, float* __restrict__ cp)
{
  __shared__ float acc[NGRAPH][HID];
  __shared__ float cl[NGRAPH];
  int t = threadIdx.x, b = blockIdx.x;
  for (int i = t; i < NGRAPH * HID; i += 256) ((float*)acc)[i] = 0.f;
  if (t < NGRAPH) cl[t] = 0.f;
  __syncthreads();
  int per = (NN + POOL_BLOCKS - 1) / POOL_BLOCKS;
  int i0 = b * per, i1 = min(NN, i0 + per);
  for (int i = i0; i < i1; ++i) {
    int g = batch[i];
    acc[g][t] += bf2f(x[(size_t)i * 256 + t]);
    if (t == 0) cl[g] += 1.f;
  }
  __syncthreads();
  for (int g = 0; g < NGRAPH; ++g) pp[(size_t)b * (NGRAPH * HID) + g * HID + t] = acc[g][t];
  if (t < NGRAPH) cp[b * NGRAPH + t] = cl[t];
}

// ---------------- head ----------------
__global__ __launch_bounds__(256) void head_k(
    const float* __restrict__ pp, const float* __restrict__ cp,
    const float* __restrict__ Wl1, const float* __restrict__ bl1,
    const float* __restrict__ Wl2, const float* __restrict__ bl2,
    float* __restrict__ out)
{
  __shared__ float pooled[HID];
  __shared__ float red[2][4];
  int g = blockIdx.x, t = threadIdx.x;
  float s = 0.f;
  for (int b = 0; b < POOL_BLOCKS; ++b) s += pp[(size_t)b * (NGRAPH * HID) + g * HID + t];
  float cnt = 0.f;
  for (int b = 0; b < POOL_BLOCKS; ++b) cnt += cp[b * NGRAPH + g];
  pooled[t] = s / fmaxf(cnt, 1.f);
  __syncthreads();
  float hv = bl1[t];
  for (int k = 0; k < HID; ++k) hv += pooled[k] * Wl1[k * HID + t];
  hv = fmaxf(hv, 0.f);
  float p0 = hv * Wl2[t * 2 + 0];
  float p1 = hv * Wl2[t * 2 + 1];
  for (int o = 32; o > 0; o >>= 1) { p0 += __shfl_down(p0, o); p1 += __shfl_down(p1, o); }
  int w = t >> 6;
  if ((t & 63) == 0) { red[0][w] = p0; red[1][w] = p1; }
  __syncthreads();
  if (t == 0) {
    float l0 = bl2[0], l1 = bl2[1];
#pragma unroll
    for (int i = 0; i < 4; i++) { l0 += red[0][i]; l1 += red[1][i]; }
    float m = fmaxf(l0, l1);
    float lse = m + logf(expf(l0 - m) + expf(l1 - m));
    out[g * 2 + 0] = l0 - lse;
    out[g * 2 + 1] = l1 - lse;
  }
}

// ---------------- launch ----------------
extern "C" void kernel_launch(void* const* d_in, const int* in_sizes, int n_in,
                              void* d_out, int out_size, void* d_ws, size_t ws_size,
                              hipStream_t stream)
{
  const float* content = (const float*)d_in[0];
  const float* bert    = (const float*)d_in[1];
  const float* profile = (const float*)d_in[2];
  const float* spacy   = (const float*)d_in[3];
  const int*   eidx    = (const int*)d_in[4];
  const int*   batch   = (const int*)d_in[5];
  const float* Wc = (const float*)d_in[6];  const float* bc = (const float*)d_in[7];
  const float* Wb = (const float*)d_in[8];  const float* bb = (const float*)d_in[9];
  const float* Wp = (const float*)d_in[10]; const float* bp = (const float*)d_in[11];
  const float* Ws = (const float*)d_in[12]; const float* bs = (const float*)d_in[13];
  const float* Wg1 = (const float*)d_in[14]; const float* bg1 = (const float*)d_in[15];
  const float* Wg2 = (const float*)d_in[16]; const float* bg2 = (const float*)d_in[17];
  const float* Wl1 = (const float*)d_in[18]; const float* bl1 = (const float*)d_in[19];
  const float* Wl2 = (const float*)d_in[20]; const float* bl2 = (const float*)d_in[21];
  float* out = (float*)d_out;
  const int* srcp = eidx;
  const int* dstp = eidx + NE;

  const int KPC = 320, KPB = 768, KPP = 64, KPS = 320, KPG1 = 1024, KPG2 = 256;

  char* ws = (char*)d_ws;
  size_t off = 0;
  auto alloc = [&](size_t bytes) { size_t o = off; off += (bytes + 255) & ~(size_t)255; return o; };

  unsigned short* WTc  = (unsigned short*)(ws + alloc((size_t)256 * KPC * 2));
  unsigned short* WTb  = (unsigned short*)(ws + alloc((size_t)256 * KPB * 2));
  unsigned short* WTp  = (unsigned short*)(ws + alloc((size_t)256 * KPP * 2));
  unsigned short* WTs  = (unsigned short*)(ws + alloc((size_t)256 * KPS * 2));
  unsigned short* WTg1 = (unsigned short*)(ws + alloc((size_t)256 * KPG1 * 2));
  unsigned short* WTg2 = (unsigned short*)(ws + alloc((size_t)256 * KPG2 * 2));
  float* dinv    = (float*)(ws + alloc((size_t)NN * 4));
  float* selfc   = (float*)(ws + alloc((size_t)NN * 4));
  int* rowcnt    = (int*)(ws + alloc((size_t)NN * 4));
  int* rowstart  = (int*)(ws + alloc((size_t)(NN + 1) * 4));
  int* cursor    = (int*)(ws + alloc((size_t)NN * 4));
  int* csr_src   = (int*)(ws + alloc((size_t)NE * 4));
  float* csr_coef= (float*)(ws + alloc((size_t)NE * 4));
  int* bsum      = (int*)(ws + alloc(1024));
  float* pp      = (float*)(ws + alloc((size_t)POOL_BLOCKS * NGRAPH * HID * 4));
  float* cp      = (float*)(ws + alloc((size_t)POOL_BLOCKS * NGRAPH * 4));
  unsigned short* X1 = (unsigned short*)(ws + alloc((size_t)NN * 1024 * 2));
  unsigned short* H  = (unsigned short*)(ws + alloc((size_t)NN * 256 * 2));
  unsigned short* X2 = (unsigned short*)(ws + alloc((size_t)NN * 256 * 2));
  unsigned short* X3 = (unsigned short*)(ws + alloc((size_t)NN * 256 * 2));
  (void)ws_size; (void)in_sizes; (void)n_in; (void)out_size;

  hipStream_t s = stream;
  const int NB = (NN + 1023) / 1024;
  const int MB = (NN + 127) / 128;    // 782

  wconv_k<<<(256 * KPC + 255) / 256, 256, 0, s>>>(Wc, WTc, 310, KPC);
  wconv_k<<<(256 * KPB + 255) / 256, 256, 0, s>>>(Wb, WTb, 768, KPB);
  wconv_k<<<(256 * KPP + 255) / 256, 256, 0, s>>>(Wp, WTp, 10, KPP);
  wconv_k<<<(256 * KPS + 255) / 256, 256, 0, s>>>(Ws, WTs, 300, KPS);
  wconv_k<<<(256 * KPG1 + 255) / 256, 256, 0, s>>>(Wg1, WTg1, 1024, KPG1);
  wconv_k<<<(256 * KPG2 + 255) / 256, 256, 0, s>>>(Wg2, WTg2, 256, KPG2);

  zero_int_k<<<(NN + 255) / 256, 256, 0, s>>>(rowcnt, NN);
  count_k<<<(NE + 255) / 256, 256, 0, s>>>(dstp, rowcnt, NE);
  deg_k<<<(NN + 255) / 256, 256, 0, s>>>(rowcnt, dinv, selfc, NN);
  scan1_k<<<NB, 256, 0, s>>>(rowcnt, bsum, NN);
  scan2_k<<<1, 256, 0, s>>>(bsum, NB);
  scan3_k<<<NB, 256, 0, s>>>(rowcnt, bsum, rowstart, cursor, NN);
  scatter_k<<<(NE + 255) / 256, 256, 0, s>>>(srcp, dstp, dinv, cursor, csr_src, csr_coef, NE);

  // fused branch linears + relu -> X1 [N,1024] bf16
  {
    GArgs gc = { content, WTc, bc, X1 + 0,   310, 310, KPC, 1024 };
    GArgs gb = { bert,    WTb, bb, X1 + 256, 768, 768, KPB, 1024 };
    GArgs gp = { profile, WTp, bp, X1 + 512, 10,  10,  KPP, 1024 };
    GArgs gs = { spacy,   WTs, bs, X1 + 768, 300, 300, KPS, 1024 };
    gemmf_k<<<dim3(MB, 2, 4), 256, 0, s>>>(gc, gb, gp, gs, NN);
  }

  // conv1: H = X1 @ Wg1 ; agg+bias+relu -> X2
  {
    GArgs g1 = { X1, WTg1, nullptr, H, 1024, 1024, KPG1, 256 };
    gemmb_k<<<dim3(MB, 2, 1), 256, 0, s>>>(g1, NN);
  }
  agg_k<<<(NN + 3) / 4, 256, 0, s>>>(H, rowstart, csr_src, csr_coef, selfc, bg1, X2);

  // conv2: H = X2 @ Wg2 ; agg+bias+relu -> X3
  {
    GArgs g2 = { X2, WTg2, nullptr, H, 256, 256, KPG2, 256 };
    gemmb_k<<<dim3(MB, 2, 1), 256, 0, s>>>(g2, NN);
  }
  agg_k<<<(NN + 3) / 4, 256, 0, s>>>(H, rowstart, csr_src, csr_coef, selfc, bg2, X3);

  pool_k<<<POOL_BLOCKS, 256, 0, s>>>(X3, batch, pp, cp);
  head_k<<<NGRAPH, 256, 0, s>>>(pp, cp, Wl1, bl1, Wl2, bl2, out);
}